// Round 9
// baseline (261.326 us; speedup 1.0000x reference)
//
#include <hip/hip_runtime.h>
#include <math.h>

#define Bb   2
#define Rr   384
#define CMd  384
#define CZ   128
#define Hh   12
#define DHd  32

#define WL           1.7320508075688772f   // sqrt(3)
#define WC           4.242640687119285f    // sqrt(18) = (2/(9*4))^-0.5
#define INV_SQRT_DH  0.17677669529663687f  // 32^-0.5

#define SZ_R   (Bb*Hh*Rr*DHd)      // 294912
#define SZ_T   (Bb*Hh*Rr*12)      // 110592
#define SZ_S   (Bb*Hh*Rr)         // 9216
#define SZ_A   ((long)Bb*Hh*Rr*Rr) // 3538944
#define SZ_O   (Bb*Rr*Hh*DHd)     // 294912

// ---------------------------------------------------------------- K1a: projection GEMM (R8 config)
__global__ __launch_bounds__(64) void k_projgemm(
    const float* __restrict__ sing, const float* __restrict__ Wqkv,
    const float* __restrict__ Wqk, float* __restrict__ pbuf)
{
  const int t = threadIdx.x;
  const int m0 = blockIdx.x * 32;
  const int n0 = blockIdx.y * 32;
  const int ks = blockIdx.z;
  const int tx = t & 7, ty = t >> 3;
  __shared__ float As[32][36];
  __shared__ float Bs[32][36];
  float acc[4][4] = {};

  for (int kc = ks*192; kc < ks*192 + 192; kc += 32) {
    #pragma unroll
    for (int i = 0; i < 4; ++i) {
      int s = t + 64*i;
      int row = s >> 3, k4 = (s & 7) << 2;
      float4 v = *(const float4*)(sing + (long)(m0 + row)*384 + kc + k4);
      As[k4  ][row] = v.x; As[k4+1][row] = v.y;
      As[k4+2][row] = v.z; As[k4+3][row] = v.w;
    }
    #pragma unroll
    for (int i = 0; i < 4; ++i) {
      int s = t + 64*i;
      int k = s >> 3, c4 = (s & 7) << 2;
      const float* srcB = (n0 < 1152)
          ? Wqkv + (long)(kc + k)*1152 + n0 + c4
          : Wqk  + (long)(kc + k)*288 + (n0 - 1152) + c4;
      float4 w = *(const float4*)srcB;
      Bs[k][c4] = w.x; Bs[k][c4+1] = w.y; Bs[k][c4+2] = w.z; Bs[k][c4+3] = w.w;
    }
    __syncthreads();
    #pragma unroll
    for (int k = 0; k < 32; ++k) {
      float4 a = *(const float4*)&As[k][ty*4];
      float4 b = *(const float4*)&Bs[k][tx*4];
      acc[0][0] += a.x*b.x; acc[0][1] += a.x*b.y; acc[0][2] += a.x*b.z; acc[0][3] += a.x*b.w;
      acc[1][0] += a.y*b.x; acc[1][1] += a.y*b.y; acc[1][2] += a.y*b.z; acc[1][3] += a.y*b.w;
      acc[2][0] += a.z*b.x; acc[2][1] += a.z*b.y; acc[2][2] += a.z*b.z; acc[2][3] += a.z*b.w;
      acc[3][0] += a.w*b.x; acc[3][1] += a.w*b.y; acc[3][2] += a.w*b.z; acc[3][3] += a.w*b.w;
    }
    __syncthreads();
  }
  float* pd = pbuf + (long)ks * (768*1440);
  #pragma unroll
  for (int i = 0; i < 4; ++i)
    *(float4*)&pd[(long)(m0 + ty*4 + i)*1440 + n0 + tx*4] =
        make_float4(acc[i][0], acc[i][1], acc[i][2], acc[i][3]);
}

// ---------------------------------------------------------------- K1a2: reduce partials + scatter
__global__ __launch_bounds__(256) void k_scatter(
    const float* __restrict__ pbuf,
    float* __restrict__ rq, float* __restrict__ rk, float* __restrict__ rv,
    float* __restrict__ gbuf)
{
  const int idx = blockIdx.x*256 + threadIdx.x;   // over 276480 float4
  const int row = idx / 360;
  const int n   = (idx - row*360) * 4;
  float4 a = ((const float4*)pbuf)[idx];
  float4 b = ((const float4*)(pbuf + (long)768*1440))[idx];
  float v[4] = {a.x + b.x, a.y + b.y, a.z + b.z, a.w + b.w};
  const int bb = row / Rr, rr = row - bb*Rr;
  #pragma unroll
  for (int j = 0; j < 4; ++j) {
    int nj = n + j;
    if (nj < 1152) {
      int d = nj/36, rem = nj - d*36, wh = rem/12, h = rem - wh*12;
      float* dst = (wh == 0) ? rq : (wh == 1) ? rk : rv;
      dst[(((long)bb*Hh + h)*Rr + rr)*DHd + d] = v[j];
    } else {
      gbuf[(long)row*288 + nj - 1152] = v[j];
    }
  }
}

// ---------------------------------------------------------------- K1b: frame transform
__global__ __launch_bounds__(256) void k_frame(
    const float* __restrict__ gbuf, const float* __restrict__ bbr,
    const float* __restrict__ bbt,
    float* __restrict__ TqF, float* __restrict__ TkF,
    float* __restrict__ Qsq, float* __restrict__ Ksq)
{
  const int idx = blockIdx.x*256 + threadIdx.x;   // 768*24 exact
  const int row = idx / 24, q = idx - row*24;
  const int h = q >> 1, s2 = q & 1;
  const float* gp = gbuf + (long)row*288 + h*24 + s2*12;
  float rot[9], tr[3];
  #pragma unroll
  for (int a = 0; a < 9; ++a) rot[a] = bbr[(long)row*9 + a];
  #pragma unroll
  for (int a = 0; a < 3; ++a) tr[a] = bbt[(long)row*3 + a];
  const int b = row / Rr, r = row - b*Rr;
  float* T = s2 ? TkF : TqF;
  const long tb = (((long)b*Hh + h)*Rr + r)*12;
  float v[12]; float ss = 0.f;
  #pragma unroll
  for (int p = 0; p < 4; ++p)
    #pragma unroll
    for (int k2 = 0; k2 < 3; ++k2) {
      float x = gp[p*3+0]*rot[k2] + gp[p*3+1]*rot[3+k2] + gp[p*3+2]*rot[6+k2] + tr[k2];
      v[p*3+k2] = x; ss += x*x;
    }
  *(float4*)(T + tb)     = make_float4(v[0], v[1], v[2],  v[3]);
  *(float4*)(T + tb + 4) = make_float4(v[4], v[5], v[6],  v[7]);
  *(float4*)(T + tb + 8) = make_float4(v[8], v[9], v[10], v[11]);
  (s2 ? Ksq : Qsq)[((long)b*Hh + h)*Rr + r] = ss;
}

// ---------------------------------------------------------------- K_mid: fused pbias + scores + softmax + agg
// one block per (b,i); pair row read once (HBM) + once (L2-hot); attn lives in LDS only.
#define JCH 48
__global__ __launch_bounds__(256) void k_mid(
    const float* __restrict__ pair, const float* __restrict__ Wfc1,
    const float* __restrict__ bfc1,
    const float* __restrict__ rq, const float* __restrict__ rk,
    const float* __restrict__ rv,
    const float* __restrict__ TqF, const float* __restrict__ TkF,
    const float* __restrict__ Qsq, const float* __restrict__ Ksq,
    const float* __restrict__ gamma,
    float* __restrict__ o_ihd, float* __restrict__ top)
{
  const int t = threadIdx.x;
  const int bi = blockIdx.x;
  const int b = bi / Rr;
  const int i = bi - b*Rr;
  const int w = t >> 6, lane = t & 63;

  __shared__ float tile[JCH][129];    // 24.2 KB; banks (j+c)%32: 2-way free
  __shared__ float attn_l[12][386];   // 18.5 KB
  __shared__ float w_l[128][12];      // 6 KB
  __shared__ float bias_l[12], qs_l[12];
  __shared__ float rq_l[12][32];
  __shared__ float tq_l[12][12];

  // stage per-row constants
  for (int idx = t; idx < 128*12; idx += 256) w_l[idx/12][idx%12] = Wfc1[idx];
  for (int idx = t; idx < 384; idx += 256) {
    int h = idx >> 5, d = idx & 31;
    rq_l[h][d] = rq[(((long)b*Hh + h)*Rr + i)*DHd + d];
  }
  if (t < 144) tq_l[t/12][t%12] = TqF[(((long)b*Hh + t/12)*Rr + i)*12 + t%12];
  if (t < 12) { bias_l[t] = bfc1[t]; qs_l[t] = Qsq[((long)b*Hh + t)*Rr + i]; }

  const float head_w = log1pf(__expf(gamma[0])) * (WC * 0.5f);
  const float* prow = pair + (long)bi * Rr * CZ;

  // ---- Phase A: pair bias -> attn_l
  for (int jc = 0; jc < Rr; jc += JCH) {
    __syncthreads();                       // tile safe to overwrite
    for (int idx = t; idx < JCH*32; idx += 256) {
      int row = idx >> 5, c4 = (idx & 31) << 2;
      float4 v = *(const float4*)(prow + (long)(jc + row)*CZ + c4);
      tile[row][c4] = v.x; tile[row][c4+1] = v.y; tile[row][c4+2] = v.z; tile[row][c4+3] = v.w;
    }
    __syncthreads();
    for (int task = t; task < JCH*12; task += 256) {
      int jj = task % JCH, h = task / JCH;
      float a = bias_l[h];
      #pragma unroll 8
      for (int c = 0; c < 128; ++c) a += tile[jj][c] * w_l[c][h];
      attn_l[h][jc + jj] = a;
    }
  }
  __syncthreads();

  // ---- Phase B: + scalar dot + point-distance term
  for (int k = 0; k < 18; ++k) {
    int tid = t + 256*k;                   // 4608 = 12*384
    int h = tid / 384, j = tid - h*384;
    const float4* kp = (const float4*)(rk + (((long)b*Hh + h)*Rr + j)*DHd);
    float dt = 0.f;
    #pragma unroll
    for (int q4 = 0; q4 < 8; ++q4) {
      float4 v = kp[q4];
      dt += rq_l[h][q4*4]*v.x + rq_l[h][q4*4+1]*v.y + rq_l[h][q4*4+2]*v.z + rq_l[h][q4*4+3]*v.w;
    }
    const float4* tk = (const float4*)(TkF + (((long)b*Hh + h)*Rr + j)*12);
    float4 ta = tk[0], tb = tk[1], tc = tk[2];
    float pt = tq_l[h][0]*ta.x + tq_l[h][1]*ta.y + tq_l[h][2]*ta.z + tq_l[h][3]*ta.w
             + tq_l[h][4]*tb.x + tq_l[h][5]*tb.y + tq_l[h][6]*tb.z + tq_l[h][7]*tb.w
             + tq_l[h][8]*tc.x + tq_l[h][9]*tc.y + tq_l[h][10]*tc.z + tq_l[h][11]*tc.w;
    float ks = Ksq[((long)b*Hh + h)*Rr + j];
    float sq = qs_l[h] + ks - 2.f*pt;
    attn_l[h][j] = WL * (attn_l[h][j] + dt*INV_SQRT_DH + head_w*sq);
  }
  __syncthreads();

  // ---- Phase C: softmax per head row (wave w handles h = w, w+4, w+8)
  #pragma unroll
  for (int r = 0; r < 3; ++r) {
    const int h = w + 4*r;
    float x[6];
    #pragma unroll
    for (int k = 0; k < 6; ++k) x[k] = attn_l[h][lane + 64*k];
    float m = x[0];
    #pragma unroll
    for (int k = 1; k < 6; ++k) m = fmaxf(m, x[k]);
    #pragma unroll
    for (int s = 32; s; s >>= 1) m = fmaxf(m, __shfl_xor(m, s, 64));
    float sum = 0.f;
    #pragma unroll
    for (int k = 0; k < 6; ++k) { x[k] = __expf(x[k] - m); sum += x[k]; }
    #pragma unroll
    for (int s = 32; s; s >>= 1) sum += __shfl_xor(sum, s, 64);
    float inv = 1.f / sum;
    #pragma unroll
    for (int k = 0; k < 6; ++k) attn_l[h][lane + 64*k] = x[k] * inv;
  }
  __syncthreads();

  // ---- Phase D: value aggregation (pair re-pass, L2-hot)
  const int c = t & 127, hh = t >> 7;        // h = hh + 2m
  float a0=0,a1=0,a2=0,a3=0,a4=0,a5=0;
  for (int jc = 0; jc < Rr; jc += JCH) {
    __syncthreads();
    for (int idx = t; idx < JCH*32; idx += 256) {
      int row = idx >> 5, c4 = (idx & 31) << 2;
      float4 v = *(const float4*)(prow + (long)(jc + row)*CZ + c4);
      tile[row][c4] = v.x; tile[row][c4+1] = v.y; tile[row][c4+2] = v.z; tile[row][c4+3] = v.w;
    }
    __syncthreads();
    #pragma unroll 4
    for (int jj = 0; jj < JCH; ++jj) {
      float v = tile[jj][c];
      int j = jc + jj;
      a0 += attn_l[hh   ][j]*v;
      a1 += attn_l[hh+2 ][j]*v;
      a2 += attn_l[hh+4 ][j]*v;
      a3 += attn_l[hh+6 ][j]*v;
      a4 += attn_l[hh+8 ][j]*v;
      a5 += attn_l[hh+10][j]*v;
    }
  }
  float* tp = top + ((long)bi*Hh)*CZ + c;
  tp[(long)(hh   )*CZ] = a0;
  tp[(long)(hh+2 )*CZ] = a1;
  tp[(long)(hh+4 )*CZ] = a2;
  tp[(long)(hh+6 )*CZ] = a3;
  tp[(long)(hh+8 )*CZ] = a4;
  tp[(long)(hh+10)*CZ] = a5;
  // Part B: o[b,i,h,d] = sum_j attn[h][j] * rv[b,h,j,d]
  for (int o = t; o < 384; o += 256) {
    int h = o >> 5, dd = o & 31;
    const float* rvp = rv + (((long)b*Hh + h)*Rr)*DHd + dd;
    float s = 0.f;
    #pragma unroll 4
    for (int j = 0; j < 384; ++j) s += attn_l[h][j] * rvp[(long)j*DHd];
    o_ihd[(long)bi*384 + o] = s;
  }
}

// ---------------------------------------------------------------- K5: output GEMM (R8 config)
#define K5_KSPLIT 6
#define K5_KLEN   320
__global__ __launch_bounds__(64) void k_final_part(
    const float* __restrict__ o_ihd, const float* __restrict__ top,
    const float* __restrict__ W0, const float* __restrict__ W1,
    float* __restrict__ partial)
{
  const int t = threadIdx.x;
  const int m0 = blockIdx.x * 32;
  const int n0 = blockIdx.y * 32;
  const int ks = blockIdx.z;
  const int tx = t & 7, ty = t >> 3;
  __shared__ float As[32][36];
  __shared__ float Bs[32][36];
  float acc[4][4] = {};

  for (int kc = ks*K5_KLEN; kc < ks*K5_KLEN + K5_KLEN; kc += 32) {
    #pragma unroll
    for (int i = 0; i < 4; ++i) {
      int s = t + 64*i;
      int row = s >> 3, k4 = (s & 7) << 2;
      int gk = kc + k4;
      const float* srcA = (gk < 384)
          ? o_ihd + (long)(m0 + row)*384 + gk
          : top   + (long)(m0 + row)*1536 + (gk - 384);
      float4 v = *(const float4*)srcA;
      As[k4  ][row] = v.x; As[k4+1][row] = v.y;
      As[k4+2][row] = v.z; As[k4+3][row] = v.w;
    }
    #pragma unroll
    for (int i = 0; i < 4; ++i) {
      int s = t + 64*i;
      int k = s >> 3, c4 = (s & 7) << 2;
      int gk = kc + k;
      const float* srcB = (gk < 384)
          ? W0 + (long)gk*384 + n0 + c4
          : W1 + (long)(gk - 384)*384 + n0 + c4;
      float4 w = *(const float4*)srcB;
      Bs[k][c4] = w.x; Bs[k][c4+1] = w.y; Bs[k][c4+2] = w.z; Bs[k][c4+3] = w.w;
    }
    __syncthreads();
    #pragma unroll
    for (int k = 0; k < 32; ++k) {
      float4 a = *(const float4*)&As[k][ty*4];
      float4 b = *(const float4*)&Bs[k][tx*4];
      acc[0][0] += a.x*b.x; acc[0][1] += a.x*b.y; acc[0][2] += a.x*b.z; acc[0][3] += a.x*b.w;
      acc[1][0] += a.y*b.x; acc[1][1] += a.y*b.y; acc[1][2] += a.y*b.z; acc[1][3] += a.y*b.w;
      acc[2][0] += a.z*b.x; acc[2][1] += a.z*b.y; acc[2][2] += a.z*b.z; acc[2][3] += a.z*b.w;
      acc[3][0] += a.w*b.x; acc[3][1] += a.w*b.y; acc[3][2] += a.w*b.z; acc[3][3] += a.w*b.w;
    }
    __syncthreads();
  }
  float* pdst = partial + (long)ks * (768*384);
  #pragma unroll
  for (int i = 0; i < 4; ++i)
    *(float4*)&pdst[(long)(m0 + ty*4 + i)*384 + n0 + tx*4] =
        make_float4(acc[i][0], acc[i][1], acc[i][2], acc[i][3]);
}

__global__ __launch_bounds__(256) void k_final_reduce(
    const float* __restrict__ partial, float* __restrict__ out)
{
  const int idx = blockIdx.x*256 + threadIdx.x;   // over 73728 float4
  float4 r = make_float4(0.f, 0.f, 0.f, 0.f);
  #pragma unroll
  for (int p = 0; p < K5_KSPLIT; ++p) {
    float4 a = ((const float4*)(partial + (long)p*768*384))[idx];
    r.x += a.x; r.y += a.y; r.z += a.z; r.w += a.w;
  }
  ((float4*)out)[idx] = r;
}

// ---------------------------------------------------------------- launch
extern "C" void kernel_launch(void* const* d_in, const int* in_sizes, int n_in,
                              void* d_out, int out_size, void* d_ws, size_t ws_size,
                              hipStream_t stream)
{
  (void)in_sizes; (void)n_in; (void)out_size; (void)ws_size;
  const float* pair  = (const float*)d_in[0];
  const float* sing  = (const float*)d_in[1];
  const float* bbr   = (const float*)d_in[2];
  const float* bbt   = (const float*)d_in[3];
  const float* Wqkv  = (const float*)d_in[4];
  const float* Wqk   = (const float*)d_in[5];
  const float* Wfc1  = (const float*)d_in[6];
  const float* bfc1  = (const float*)d_in[7];
  const float* W0    = (const float*)d_in[8];
  const float* W1    = (const float*)d_in[9];
  const float* gamma = (const float*)d_in[10];
  float* out = (float*)d_out;

  float* ws    = (float*)d_ws;
  float* rq    = ws;
  float* rk    = rq  + SZ_R;
  float* rv    = rk  + SZ_R;
  float* TqF   = rv  + SZ_R;
  float* TkF   = TqF + SZ_T;
  float* Qsq   = TkF + SZ_T;
  float* Ksq   = Qsq + SZ_S;
  float* scr   = Ksq + SZ_S;       // big scratch (old attn region)
  float* o_ihd = scr + SZ_A;
  float* top   = o_ihd + SZ_O;
  float* gbuf  = o_ihd;     // alias: consumed by k_frame before k_mid writes o_ihd
  float* pbuf  = scr;       // 2*768*1440 = 2.21M floats < SZ_A
  float* partial = scr;     // 6*294912 = 1.77M < SZ_A; scr dead after k_scatter

  k_projgemm<<<dim3(24, 45, 2), dim3(64), 0, stream>>>(sing, Wqkv, Wqk, pbuf);
  k_scatter<<<dim3(276480/256), dim3(256), 0, stream>>>(pbuf, rq, rk, rv, gbuf);
  k_frame<<<dim3(Bb*Rr*24/256), dim3(256), 0, stream>>>(
      gbuf, bbr, bbt, TqF, TkF, Qsq, Ksq);
  k_mid<<<dim3(Bb*Rr), dim3(256), 0, stream>>>(
      pair, Wfc1, bfc1, rq, rk, rv, TqF, TkF, Qsq, Ksq, gamma, o_ihd, top);
  k_final_part<<<dim3(24, 12, K5_KSPLIT), dim3(64), 0, stream>>>(
      o_ihd, top, W0, W1, partial);
  k_final_reduce<<<dim3(768*384/4/256), dim3(256), 0, stream>>>(partial, out);
}